// Round 1
// baseline (316.348 us; speedup 1.0000x reference)
//
#include <hip/hip_runtime.h>
#include <hip/hip_bf16.h>
#include <stdint.h>

typedef __attribute__((ext_vector_type(8))) short bf16x8;
typedef __attribute__((ext_vector_type(4))) float f32x4;

__device__ __forceinline__ unsigned short f2bf(float f) {
    union { float f; unsigned u; } v; v.f = f;
    unsigned u = v.u;
    u += 0x7fff + ((u >> 16) & 1);   // round-to-nearest-even
    return (unsigned short)(u >> 16);
}

// ---------------------------------------------------------------------------
// MLP layer: out = act(A @ W^T + b).  A: (M,256) fp32, W: (256,256) fp32 row-
// major (n,k).  BM=32, BN=64, full K staged in LDS (stride 264 = 2-way-free).
// ---------------------------------------------------------------------------
template<bool RELU, bool OUT_BF16>
__global__ __launch_bounds__(256) void mlp_layer(
    const float* __restrict__ A, const float* __restrict__ W,
    const float* __restrict__ bias, void* __restrict__ out, int M)
{
    __shared__ unsigned short Asm[32 * 264];
    __shared__ unsigned short Wsm[64 * 264];
    const int tid = threadIdx.x;
    const int m0 = blockIdx.x * 32;
    const int n0 = blockIdx.y * 64;

    // stage A: 32x256 fp32 -> bf16 (2048 float4 chunks, 8/thread)
    #pragma unroll
    for (int i = 0; i < 8; ++i) {
        int c = tid + i * 256;
        int row = c >> 6;            // 64 float4 per row
        int kq  = (c & 63) * 4;
        float4 v = make_float4(0.f, 0.f, 0.f, 0.f);
        if (m0 + row < M) v = *(const float4*)(A + (size_t)(m0 + row) * 256 + kq);
        unsigned short* dst = &Asm[row * 264 + kq];
        dst[0] = f2bf(v.x); dst[1] = f2bf(v.y); dst[2] = f2bf(v.z); dst[3] = f2bf(v.w);
    }
    // stage W: 64x256 fp32 -> bf16 (4096 float4 chunks, 16/thread)
    #pragma unroll
    for (int i = 0; i < 16; ++i) {
        int c = tid + i * 256;
        int row = c >> 6;
        int kq  = (c & 63) * 4;
        float4 v = *(const float4*)(W + (size_t)(n0 + row) * 256 + kq);
        unsigned short* dst = &Wsm[row * 264 + kq];
        dst[0] = f2bf(v.x); dst[1] = f2bf(v.y); dst[2] = f2bf(v.z); dst[3] = f2bf(v.w);
    }
    __syncthreads();

    const int wid = tid >> 6, lane = tid & 63;
    const int wm = wid >> 1, wn = wid & 1;
    const int quad = lane >> 4, l16 = lane & 15;

    f32x4 acc[2] = {};
    const unsigned short* arow = &Asm[(wm * 16 + l16) * 264 + quad * 8];
    const unsigned short* brow = &Wsm[(wn * 32 + l16) * 264 + quad * 8];
    #pragma unroll
    for (int k = 0; k < 256; k += 32) {
        bf16x8 af = *(const bf16x8*)(arow + k);
        #pragma unroll
        for (int t = 0; t < 2; ++t) {
            bf16x8 bf = *(const bf16x8*)(brow + t * 16 * 264 + k);
            acc[t] = __builtin_amdgcn_mfma_f32_16x16x32_bf16(af, bf, acc[t], 0, 0, 0);
        }
    }

    #pragma unroll
    for (int t = 0; t < 2; ++t) {
        int n = n0 + wn * 32 + t * 16 + l16;
        float bv = bias[n];
        #pragma unroll
        for (int r = 0; r < 4; ++r) {
            int m = m0 + wm * 16 + quad * 4 + r;
            if (m < M) {
                float v = acc[t][r] + bv;
                if (RELU) v = fmaxf(v, 0.f);
                if (OUT_BF16) ((unsigned short*)out)[(size_t)m * 256 + n] = f2bf(v);
                else          ((float*)out)[(size_t)m * 256 + n] = v;
            }
        }
    }
}

// ---------------------------------------------------------------------------
// Fused logits GEMM + scatter-add.
// Block: 64 features x full Q (19 tiles of 16 = 304 padded cols).
// C[m,n] = dot(FV[base+m], QB[qoff[b]+n]); epilogue atomically adds row m's
// logits at out[(b*H + h)*W + w][:] per feature_indices.
// ---------------------------------------------------------------------------
__global__ __launch_bounds__(256) void logits_scatter(
    const float* __restrict__ FV,            // (NF,256) fp32
    const int* __restrict__ FI,              // (NF,3) [b,h,w]
    const unsigned short* __restrict__ QB,   // (NQ,256) bf16
    const int* __restrict__ qoff,            // (B+1)
    const int* __restrict__ hptr, const int* __restrict__ wptr,
    float* __restrict__ out, int NF, int Bc, int out_size)
{
    __shared__ unsigned short Asm[64 * 56];    // 64 rows x BK=32, stride 56
    __shared__ unsigned short Bsm[304 * 56];   // 304 rows x BK=32, stride 56

    const int tid  = threadIdx.x;
    const int base = blockIdx.x * 64;
    const int H = *hptr, Wd = *wptr;
    const int Qstride = out_size / (Bc * H * Wd);
    const int b    = FI[(size_t)base * 3];     // batch of this feature tile
    const int q0   = qoff[b];
    const int qlen = qoff[b + 1] - q0;

    const int wid = tid >> 6, lane = tid & 63;
    const int quad = lane >> 4, l16 = lane & 15;

    f32x4 acc[19] = {};

    for (int k0 = 0; k0 < 256; k0 += 32) {
        // stage A: 64x32 fp32 -> bf16 (512 float4 chunks, 2/thread)
        #pragma unroll
        for (int i = 0; i < 2; ++i) {
            int c = tid + i * 256;
            int row = c >> 3;                 // 8 float4 per row
            int kq  = (c & 7) * 4;
            int gr  = base + row;
            float4 v = make_float4(0.f, 0.f, 0.f, 0.f);
            if (gr < NF) v = *(const float4*)(FV + (size_t)gr * 256 + k0 + kq);
            unsigned short* dst = &Asm[row * 56 + kq];
            dst[0] = f2bf(v.x); dst[1] = f2bf(v.y); dst[2] = f2bf(v.z); dst[3] = f2bf(v.w);
        }
        // stage B: 304 rows x 32 k of bf16 queries (1216 16B chunks)
        for (int c = tid; c < 1216; c += 256) {
            int row = c >> 2;
            int kc  = (c & 3) * 8;
            uint4 v = make_uint4(0u, 0u, 0u, 0u);
            if (row < qlen) v = *(const uint4*)(QB + (size_t)(q0 + row) * 256 + k0 + kc);
            *(uint4*)&Bsm[row * 56 + kc] = v;
        }
        __syncthreads();

        bf16x8 af = *(const bf16x8*)(&Asm[(wid * 16 + l16) * 56 + quad * 8]);
        #pragma unroll
        for (int t = 0; t < 19; ++t) {
            bf16x8 bf = *(const bf16x8*)(&Bsm[(t * 16 + l16) * 56 + quad * 8]);
            acc[t] = __builtin_amdgcn_mfma_f32_16x16x32_bf16(af, bf, acc[t], 0, 0, 0);
        }
        __syncthreads();
    }

    // epilogue: scatter-add each feature row's logits into out[b,h,w,:]
    #pragma unroll
    for (int r = 0; r < 4; ++r) {
        int m  = wid * 16 + quad * 4 + r;
        int nf = base + m;
        if (nf < NF) {
            int hh = FI[(size_t)nf * 3 + 1];
            int ww = FI[(size_t)nf * 3 + 2];
            float* dst = out + ((size_t)(b * H + hh) * Wd + ww) * Qstride;
            #pragma unroll
            for (int t = 0; t < 19; ++t) {
                int n = t * 16 + l16;
                if (n < qlen) atomicAdd(dst + n, acc[t][r]);
            }
        }
    }
}

extern "C" void kernel_launch(void* const* d_in, const int* in_sizes, int n_in,
                              void* d_out, int out_size, void* d_ws, size_t ws_size,
                              hipStream_t stream) {
    const float* queries = (const float*)d_in[0];
    const float* FV      = (const float*)d_in[1];
    const int*   FI      = (const int*)d_in[2];
    const int*   qoff    = (const int*)d_in[3];
    const int*   hptr    = (const int*)d_in[5];
    const int*   wptr    = (const int*)d_in[6];
    const float* W0 = (const float*)d_in[7];
    const float* b0 = (const float*)d_in[8];
    const float* W1 = (const float*)d_in[9];
    const float* b1 = (const float*)d_in[10];
    const float* W2 = (const float*)d_in[11];
    const float* b2 = (const float*)d_in[12];
    const float* W3 = (const float*)d_in[13];
    const float* b3 = (const float*)d_in[14];
    float* out = (float*)d_out;

    const int NQ = in_sizes[0] / 256;   // 1200
    const int NF = in_sizes[1] / 256;   // 65536
    const int Bc = in_sizes[3] - 1;     // 4

    float* ws0 = (float*)d_ws;
    float* ws1 = ws0 + (size_t)NQ * 256;
    unsigned short* wsb = (unsigned short*)(ws1 + (size_t)NQ * 256);

    hipMemsetAsync(d_out, 0, (size_t)out_size * sizeof(float), stream);

    dim3 mgrid((NQ + 31) / 32, 4);
    mlp_layer<true,  false><<<mgrid, 256, 0, stream>>>(queries, W0, b0, ws0, NQ);
    mlp_layer<true,  false><<<mgrid, 256, 0, stream>>>(ws0,     W1, b1, ws1, NQ);
    mlp_layer<true,  false><<<mgrid, 256, 0, stream>>>(ws1,     W2, b2, ws0, NQ);
    mlp_layer<false, true ><<<mgrid, 256, 0, stream>>>(ws0,     W3, b3, wsb, NQ);

    logits_scatter<<<dim3((NF + 63) / 64), 256, 0, stream>>>(
        FV, FI, wsb, qoff, hptr, wptr, out, NF, Bc, out_size);
}